// Round 8
// baseline (138.485 us; speedup 1.0000x reference)
//
#include <hip/hip_runtime.h>
#include <hip/hip_bf16.h>
#include <math.h>

// Problem constants (B=2, L=2048, H=16, D=64, HID=1024, NB=4)
#define NBL   4096      // B*L
#define NPOS  65536     // B*L*H
#define TWO_D 128
#define HIDN  1024

typedef __attribute__((ext_vector_type(8))) short short8;   // 8 bf16 (4 VGPRs)
typedef __attribute__((ext_vector_type(4))) short short4v;  // 4 bf16 (8B)
typedef __attribute__((ext_vector_type(4))) float f32x4;    // MFMA accumulator
typedef __attribute__((ext_vector_type(4))) unsigned int uint4v;

// fp32 -> bf16 RNE (scalar)
__device__ inline short f2bf(float f) {
    union { float f; unsigned u; } v; v.f = f;
    unsigned r = (v.u + 0x7FFFu + ((v.u >> 16) & 1u)) >> 16;
    return (short)r;
}
// packed fp32x2 -> bf16x2 (hardware v_cvt_pk_bf16_f32)
__device__ inline unsigned pkbf(float x, float y) {
    __hip_bfloat162 h = __float22bfloat162_rn(make_float2(x, y));
    union { __hip_bfloat162 h; unsigned u; } c; c.h = h;
    return c.u;
}
// fast GELU (tanh form): x * sigmoid(1.5957691*(x + 0.044715 x^3))
__device__ inline float gelu_fast(float x) {
    const float x2 = x * x;
    const float u  = x * fmaf(x2, 0.044715f, 1.0f) * 1.5957691216057308f;
    const float e  = __expf(-u);
    return x * __builtin_amdgcn_rcpf(1.0f + e);
}

// ws layout (bytes):
//   hP   : float [8][4096][128]   @ 0           (16,777,216)  hid K-eighth partials
//   wsT  : bf16  [128][32]        @ 16,777,216  (8,192)

// ---------------------------------------------------------------- K1: hid GEMM + wsum
// blocks 0..511 : ks = b>>6 (K-eighth), mg = b&63 (4 m-tiles). 256 thr = 4 waves.
//                 Self-transposes W1[ks*128..+128][0..128) -> LDS bf16, then MFMA.
// blocks 512..523: wsum column (b-512) -> wsT (k_prep folded in).
__global__ __launch_bounds__(256, 4) void k_hid(const float* __restrict__ hidden,
                                                const float* __restrict__ W1,
                                                float* __restrict__ hP,
                                                short* __restrict__ wsT) {
    __shared__ short wbh[128 * 136];                // 34,816 B
    __shared__ float acc2[128];
    const int b = blockIdx.x, t = threadIdx.x;

    if (b >= 512) {                                 // ---- wsum blocks
        const int i = b - 512;                      // 0..11
        const int j = i / 3, sx = i - 3 * j;
        const int base = HIDN + j * 192 + sx * 64;
        const int n = t & 127, dh = t >> 7;
        float s = 0.f;
        for (int d = 0; d < 32; ++d)
            s += W1[(size_t)(base + dh * 32 + d) * TWO_D + n];  // coalesced
        if (dh) acc2[n] = s;
        __syncthreads();
        if (!dh) {
            wsT[n * 32 + i] = f2bf(s + acc2[n]);
            if (i == 0)
                for (int p = 12; p < 32; ++p) wsT[n * 32 + p] = (short)0;
        }
        return;
    }

    const int ks   = b >> 6;                        // K-eighth 0..7
    const int mg   = b & 63;
    const int lane = t & 63;
    const int w    = __builtin_amdgcn_readfirstlane(t >> 6);   // 0..3
    const int quad = lane >> 4, lm = lane & 15;

    // ---- stage: transpose W1 rows [ks*128, +128) x cols [0,128) -> wbh[n][k]
    {
        const int n = t & 127, g = t >> 7;          // g in {0,1}
        #pragma unroll
        for (int i = 0; i < 16; ++i) {
            const int kb = i * 8 + g * 4;           // local k base
            const float v0 = W1[(size_t)(ks * 128 + kb + 0) * TWO_D + n];
            const float v1 = W1[(size_t)(ks * 128 + kb + 1) * TWO_D + n];
            const float v2 = W1[(size_t)(ks * 128 + kb + 2) * TWO_D + n];
            const float v3 = W1[(size_t)(ks * 128 + kb + 3) * TWO_D + n];
            union { short4v s; unsigned u[2]; } pk;
            pk.u[0] = pkbf(v0, v1);
            pk.u[1] = pkbf(v2, v3);
            *(short4v*)(wbh + n * 136 + kb) = pk.s;
        }
    }
    __syncthreads();

    const int r0 = (mg * 4 + w) * 16;
    f32x4 acc[8];
    #pragma unroll
    for (int nt = 0; nt < 8; ++nt) acc[nt] = (f32x4){0.f, 0.f, 0.f, 0.f};

    #pragma unroll
    for (int kk = 0; kk < 4; ++kk) {
        const int kl = kk * 32 + quad * 8;          // local k
        const int kG = ks * 128 + kl;
        const float4 x0 = *(const float4*)(hidden + (size_t)(r0 + lm) * HIDN + kG);
        const float4 x1 = *(const float4*)(hidden + (size_t)(r0 + lm) * HIDN + kG + 4);
        union { short8 s; uint4v u; } a;
        a.u = (uint4v){pkbf(x0.x, x0.y), pkbf(x0.z, x0.w),
                       pkbf(x1.x, x1.y), pkbf(x1.z, x1.w)};
        #pragma unroll
        for (int nt = 0; nt < 8; ++nt) {
            const short8 bfr = *(const short8*)(wbh + (nt * 16 + lm) * 136 + kl);
            acc[nt] = __builtin_amdgcn_mfma_f32_16x16x32_bf16(a.s, bfr, acc[nt], 0, 0, 0);
        }
    }

    float* __restrict__ dst = hP + (size_t)ks * NBL * TWO_D;
    #pragma unroll
    for (int nt = 0; nt < 8; ++nt)
        #pragma unroll
        for (int r = 0; r < 4; ++r)
            dst[(size_t)(r0 + quad * 4 + r) * TWO_D + nt * 16 + lm] = acc[nt][r];
}

// ---------------------------------------------------------------- K2: main fused kernel
// grid 512 x 512 thr (8 waves). Wave = one (b,l) m-tile (16 heads).
// Stage phase: self-transpose W1 branch rows -> LDS, reduce 8 hP slices -> LDS,
// W2/b1 -> LDS. Then branch GEMM + stat k-step + epilogue.
__global__ __launch_bounds__(512, 4) void k_main(
    const float* __restrict__ g0, const float* __restrict__ g1,
    const float* __restrict__ g2, const float* __restrict__ g3,
    const float* __restrict__ W1, const short* __restrict__ wsT,
    const float* __restrict__ b1, const float* __restrict__ W2,
    const float* __restrict__ b2, const float* __restrict__ eps_floor,
    const float* __restrict__ temp, const float* __restrict__ hP,
    float* __restrict__ out) {

    __shared__ short wb[128 * 264];                 // 67,584 B
    __shared__ float hids[1024];                    //  4,096 B
    __shared__ float w2s[512];                      //  2,048 B
    __shared__ float b1s[128];                      //    512 B

    const int t    = threadIdx.x;
    const int lane = t & 63;
    const int w    = __builtin_amdgcn_readfirstlane(t >> 6);   // 0..7
    const int quad = lane >> 4, lm = lane & 15;
    const int bl   = blockIdx.x * 8 + w;            // (b,l) index = m-tile
    const int pos0 = bl * 16;

    // ---- stage: transpose W1 rows 1792..2048 x cols 0..128 -> wb[n][k]
    {
        const int n = t & 127, g = t >> 7;          // g in 0..3
        #pragma unroll
        for (int i = 0; i < 16; ++i) {
            const int kb = i * 16 + g * 4;          // k base 0..255
            const float v0 = W1[(size_t)(1792 + kb + 0) * TWO_D + n];
            const float v1 = W1[(size_t)(1792 + kb + 1) * TWO_D + n];
            const float v2 = W1[(size_t)(1792 + kb + 2) * TWO_D + n];
            const float v3 = W1[(size_t)(1792 + kb + 3) * TWO_D + n];
            union { short4v s; unsigned u[2]; } pk;
            pk.u[0] = pkbf(v0, v1);
            pk.u[1] = pkbf(v2, v3);
            *(short4v*)(wb + n * 264 + kb) = pk.s;
        }
    }
    // ---- stage: reduce 8 hP slices for this block's 8 bl rows -> hids
    #pragma unroll
    for (int e = 0; e < 2; ++e) {
        const int idx = e * 512 + t;                // 0..1023 = (bl_local, n)
        const int bll = idx >> 7, nn = idx & 127;
        const size_t base = (size_t)(blockIdx.x * 8 + bll) * TWO_D + nn;
        float hv = 0.f;
        #pragma unroll
        for (int s = 0; s < 8; ++s) hv += hP[(size_t)s * 524288 + base];
        hids[bll * 128 + nn] = hv;
    }
    w2s[t] = W2[t];
    if (t < 128) b1s[t] = b1[t];
    __syncthreads();

    f32x4 acc[8];
    #pragma unroll
    for (int nt = 0; nt < 8; ++nt) acc[nt] = (f32x4){0.f, 0.f, 0.f, 0.f};

    float stm[12];
    const float* const bjs[4] = {g0, g1, g2, g3};
    #pragma unroll
    for (int j = 0; j < 4; ++j) {
        const float* __restrict__ bj = bjs[j];
        float s = 0.f, sq = 0.f, mx = -INFINITY;
        #pragma unroll
        for (int half = 0; half < 2; ++half) {
            const int kc = half * 32 + quad * 8;
            const float4 x0 = *(const float4*)(bj + (size_t)(pos0 + lm) * 64 + kc);
            const float4 x1 = *(const float4*)(bj + (size_t)(pos0 + lm) * 64 + kc + 4);
            s  += x0.x + x0.y + x0.z + x0.w + x1.x + x1.y + x1.z + x1.w;
            sq  = fmaf(x0.x, x0.x, sq); sq = fmaf(x0.y, x0.y, sq);
            sq  = fmaf(x0.z, x0.z, sq); sq = fmaf(x0.w, x0.w, sq);
            sq  = fmaf(x1.x, x1.x, sq); sq = fmaf(x1.y, x1.y, sq);
            sq  = fmaf(x1.z, x1.z, sq); sq = fmaf(x1.w, x1.w, sq);
            mx  = fmaxf(mx, fmaxf(fmaxf(x0.x, x0.y), fmaxf(x0.z, x0.w)));
            mx  = fmaxf(mx, fmaxf(fmaxf(x1.x, x1.y), fmaxf(x1.z, x1.w)));
            union { short8 s; uint4v u; } a;
            a.u = (uint4v){pkbf(x0.x, x0.y), pkbf(x0.z, x0.w),
                           pkbf(x1.x, x1.y), pkbf(x1.z, x1.w)};
            const int kg = j * 64 + half * 32 + quad * 8;
            #pragma unroll
            for (int nt = 0; nt < 8; ++nt) {
                const short8 bfr = *(const short8*)(wb + (nt * 16 + lm) * 264 + kg);
                acc[nt] = __builtin_amdgcn_mfma_f32_16x16x32_bf16(a.s, bfr, acc[nt], 0, 0, 0);
            }
        }
        float ss = s, qq = sq, mm = mx;
        ss += __shfl_xor(ss, 16); ss += __shfl_xor(ss, 32);
        qq += __shfl_xor(qq, 16); qq += __shfl_xor(qq, 32);
        mm  = fmaxf(mm, __shfl_xor(mm, 16)); mm = fmaxf(mm, __shfl_xor(mm, 32));
        stm[3 * j + 0] = ss * (1.f / 64.f);
        stm[3 * j + 1] = sqrtf(fmaxf(qq * (1.f / 64.f), 1e-8f));
        stm[3 * j + 2] = mm;
    }

    // stat k-step via wsT (L2-resident global)
    {
        short8 sa;
        #pragma unroll
        for (int jj = 0; jj < 8; ++jj) {
            float v;
            if (jj < 4) v = (quad == 0) ? stm[jj] : ((quad == 1) ? stm[8 + jj] : 0.f);
            else        v = (quad == 0) ? stm[jj] : 0.f;
            sa[jj] = f2bf(v);
        }
        #pragma unroll
        for (int nt = 0; nt < 8; ++nt) {
            const short8 bfr = *(const short8*)(wsT + (size_t)(nt * 16 + lm) * 32 + quad * 8);
            acc[nt] = __builtin_amdgcn_mfma_f32_16x16x32_bf16(sa, bfr, acc[nt], 0, 0, 0);
        }
    }

    // ---- epilogue: + hid (LDS) + b1, fast GELU, W2 partials, reduce, softmax
    const float4 b2v = *(const float4*)b2;
    float tcl[4]; float4 efl[4];
    #pragma unroll
    for (int r = 0; r < 4; ++r) {
        const int h = quad * 4 + r;
        tcl[r] = fminf(fmaxf(temp[h], 0.2f), 10.0f);
        efl[r] = *(const float4*)(eps_floor + h * 4);
    }

    float p[4][4];
    #pragma unroll
    for (int r = 0; r < 4; ++r)
        #pragma unroll
        for (int c = 0; c < 4; ++c) p[r][c] = 0.f;

    #pragma unroll
    for (int nt = 0; nt < 8; ++nt) {
        const int n = nt * 16 + lm;
        const float hv  = hids[w * 128 + n];
        const float b1v = b1s[n];
        const float4 w2v = *(const float4*)(w2s + n * 4);
        #pragma unroll
        for (int r = 0; r < 4; ++r) {
            const float x = acc[nt][r] + hv + b1v;
            const float g = gelu_fast(x);
            p[r][0] = fmaf(g, w2v.x, p[r][0]);
            p[r][1] = fmaf(g, w2v.y, p[r][1]);
            p[r][2] = fmaf(g, w2v.z, p[r][2]);
            p[r][3] = fmaf(g, w2v.w, p[r][3]);
        }
    }
    #pragma unroll
    for (int r = 0; r < 4; ++r)
        #pragma unroll
        for (int c = 0; c < 4; ++c) {
            float v = p[r][c];
            v += __shfl_xor(v, 1); v += __shfl_xor(v, 2);
            v += __shfl_xor(v, 4); v += __shfl_xor(v, 8);
            p[r][c] = v;
        }

    #pragma unroll
    for (int r = 0; r < 4; ++r) {
        const float l0 = p[r][0] + b2v.x;
        const float l1 = p[r][1] + b2v.y;
        const float l2 = p[r][2] + b2v.z;
        const float l3 = p[r][3] + b2v.w;
        const float inv = 1.0f / tcl[r];
        const float m = fmaxf(fmaxf(l0, l1), fmaxf(l2, l3));
        float e0 = __expf((l0 - m) * inv);
        float e1 = __expf((l1 - m) * inv);
        float e2 = __expf((l2 - m) * inv);
        float e3 = __expf((l3 - m) * inv);
        const float rsum = 1.0f / (e0 + e1 + e2 + e3);
        float w0 = e0 * rsum, w1 = e1 * rsum, w2 = e2 * rsum, w3 = e3 * rsum;
        w0 = fmaxf(w0, fminf(fmaxf(efl[r].x, 1e-7f), 0.1f));
        w1 = fmaxf(w1, fminf(fmaxf(efl[r].y, 1e-7f), 0.1f));
        w2 = fmaxf(w2, fminf(fmaxf(efl[r].z, 1e-7f), 0.1f));
        w3 = fmaxf(w3, fminf(fmaxf(efl[r].w, 1e-7f), 0.1f));
        const float rs = 1.0f / (w0 + w1 + w2 + w3);
        if (lm == 0) {
            const int pos = pos0 + quad * 4 + r;
            float4 ov; ov.x = w0 * rs; ov.y = w1 * rs; ov.z = w2 * rs; ov.w = w3 * rs;
            *(float4*)(out + (size_t)pos * 4) = ov;
        }
    }
}

// ---------------------------------------------------------------- launch
extern "C" void kernel_launch(void* const* d_in, const int* in_sizes, int n_in,
                              void* d_out, int out_size, void* d_ws, size_t ws_size,
                              hipStream_t stream) {
    const float* hidden = (const float*)d_in[0];
    const float* br0    = (const float*)d_in[1];
    const float* br1    = (const float*)d_in[2];
    const float* br2    = (const float*)d_in[3];
    const float* br3    = (const float*)d_in[4];
    const float* W1     = (const float*)d_in[5];
    const float* b1     = (const float*)d_in[6];
    const float* W2     = (const float*)d_in[7];
    const float* b2     = (const float*)d_in[8];
    const float* eps    = (const float*)d_in[9];
    const float* temp   = (const float*)d_in[10];
    float* out = (float*)d_out;

    char* wsb = (char*)d_ws;
    float* hP  = (float*)(wsb);
    short* wsT = (short*)(wsb + 16777216);

    hipLaunchKernelGGL(k_hid,  dim3(524), dim3(256), 0, stream, hidden, W1, hP, wsT);
    hipLaunchKernelGGL(k_main, dim3(512), dim3(512), 0, stream,
                       br0, br1, br2, br3, W1, wsT, b1, W2, b2, eps, temp,
                       hP, out);
}